// Round 1
// baseline (472.889 us; speedup 1.0000x reference)
//
#include <hip/hip_runtime.h>
#include <math.h>
#include <stdint.h>

#define NPTS   524288
#define TSZ    524288u
#define HMASK  (TSZ - 1u)
#define PRIME1 2654435761u
#define PRIME2 805459861u
#define NLVL   24

struct ResParams { float r[NLVL]; };

// LDS layout (float offsets), all segment starts multiple of 4 (16B aligned)
#define OFF_W0   0      // 48*32 = 1536
#define OFF_B0   1536   // 32
#define OFF_W1   1568   // 32*32 = 1024
#define OFF_B1   2592   // 32
#define OFF_W2   2624   // 1024
#define OFF_B2   3648   // 32
#define OFF_W3T  3680   // transposed [33][32] = 1056
#define OFF_B3   4736   // 33 (pad->36)
#define OFF_EW0  4772   // 2*32*32 = 2048
#define OFF_EB0  6820   // 64
#define OFF_EW1  6884   // 64
#define OFF_EB1  6948   // 2 (pad->4)
#define SMEM_FLOATS 6952

__device__ __forceinline__ float softplus_f(float x) {
    // jax.nn.softplus = logaddexp(x, 0) = max(x,0) + log1p(exp(-|x|))
    return fmaxf(x, 0.f) + log1pf(expf(-fabsf(x)));
}

__global__ __launch_bounds__(256)
void fused_offsets_sdf(const float* __restrict__ points,
                       const float* __restrict__ table,
                       const float* __restrict__ W0, const float* __restrict__ b0,
                       const float* __restrict__ W1, const float* __restrict__ b1,
                       const float* __restrict__ W2, const float* __restrict__ b2,
                       const float* __restrict__ W3, const float* __restrict__ b3,
                       const float* __restrict__ eW0, const float* __restrict__ eb0,
                       const float* __restrict__ eW1, const float* __restrict__ eb1,
                       float* __restrict__ out, ResParams rp)
{
    __shared__ __align__(16) float sm[SMEM_FLOATS];
    const int t = threadIdx.x;

    // ---- cooperative weight staging into LDS ----
    for (int i = t; i < 1536; i += 256) sm[OFF_W0 + i] = W0[i];
    for (int i = t; i < 32;   i += 256) sm[OFF_B0 + i] = b0[i];
    for (int i = t; i < 1024; i += 256) sm[OFF_W1 + i] = W1[i];
    for (int i = t; i < 32;   i += 256) sm[OFF_B1 + i] = b1[i];
    for (int i = t; i < 1024; i += 256) sm[OFF_W2 + i] = W2[i];
    for (int i = t; i < 32;   i += 256) sm[OFF_B2 + i] = b2[i];
    for (int i = t; i < 1056; i += 256) {          // transpose W3 (32x33) -> [33][32]
        int r_ = i / 33, c_ = i % 33;
        sm[OFF_W3T + c_ * 32 + r_] = W3[i];
    }
    for (int i = t; i < 33;   i += 256) sm[OFF_B3 + i] = b3[i];
    for (int i = t; i < 2048; i += 256) sm[OFF_EW0 + i] = eW0[i];
    for (int i = t; i < 64;   i += 256) sm[OFF_EB0 + i] = eb0[i];
    for (int i = t; i < 64;   i += 256) sm[OFF_EW1 + i] = eW1[i];
    for (int i = t; i < 2;    i += 256) sm[OFF_EB1 + i] = eb1[i];
    __syncthreads();

    const int pid = blockIdx.x * 256 + t;

    const float px = points[pid * 3 + 0];
    const float py = points[pid * 3 + 1];
    const float pz = points[pid * 3 + 2];
    const float x0 = px * 0.5f + 0.5f;   // /BB + 0.5, BB=2 (exact)
    const float y0 = py * 0.5f + 0.5f;
    const float z0 = pz * 0.5f + 0.5f;

    // ---- layer-0 accumulator; hash features folded in directly (enc never materialized)
    float h0[32];
    #pragma unroll
    for (int o = 0; o < 32; ++o) h0[o] = sm[OFF_B0 + o];

    #pragma unroll 2
    for (int l = 0; l < NLVL; ++l) {
        const float res = rp.r[l];
        const float sx = x0 * res, sy = y0 * res, sz = z0 * res;
        const float fx = floorf(sx), fy = floorf(sy), fz = floorf(sz);
        const float tx = sx - fx,  ty = sy - fy,  tz = sz - fz;
        const uint32_t cx = (uint32_t)fx, cy = (uint32_t)fy, cz = (uint32_t)fz;
        const uint32_t hy0 = cy * PRIME1, hy1 = (cy + 1u) * PRIME1;
        const uint32_t hz0 = cz * PRIME2, hz1 = (cz + 1u) * PRIME2;
        const float wx[2] = {1.f - tx, tx};
        const float wy[2] = {1.f - ty, ty};
        const float wz[2] = {1.f - tz, tz};
        const float* tl = table + (size_t)l * (size_t)(TSZ * 2u);

        float a0 = 0.f, a1 = 0.f;
        #pragma unroll
        for (int corner = 0; corner < 8; ++corner) {
            const uint32_t dx = (uint32_t)(corner & 1);
            const uint32_t dy = (uint32_t)((corner >> 1) & 1);
            const uint32_t dz = (uint32_t)((corner >> 2) & 1);
            const uint32_t idx = ((cx + dx) ^ (dy ? hy1 : hy0) ^ (dz ? hz1 : hz0)) & HMASK;
            const float2 f2 = *reinterpret_cast<const float2*>(tl + (size_t)idx * 2u);
            const float w = wx[dx] * wy[dy] * wz[dz];
            a0 = fmaf(w, f2.x, a0);
            a1 = fmaf(w, f2.y, a1);
        }
        // fold level features into layer-0 pre-activation: h0 += a0*W0[2l,:] + a1*W0[2l+1,:]
        const float4* w0a = reinterpret_cast<const float4*>(&sm[OFF_W0 + (2 * l) * 32]);
        const float4* w0b = reinterpret_cast<const float4*>(&sm[OFF_W0 + (2 * l + 1) * 32]);
        #pragma unroll
        for (int o4 = 0; o4 < 8; ++o4) {
            const float4 wa = w0a[o4];
            const float4 wb = w0b[o4];
            h0[4*o4+0] = fmaf(a0, wa.x, fmaf(a1, wb.x, h0[4*o4+0]));
            h0[4*o4+1] = fmaf(a0, wa.y, fmaf(a1, wb.y, h0[4*o4+1]));
            h0[4*o4+2] = fmaf(a0, wa.z, fmaf(a1, wb.z, h0[4*o4+2]));
            h0[4*o4+3] = fmaf(a0, wa.w, fmaf(a1, wb.w, h0[4*o4+3]));
        }
    }
    #pragma unroll
    for (int o = 0; o < 32; ++o) h0[o] = fmaxf(h0[o], 0.f);

    // ---- layer 1: h1 = relu(h0 @ W1 + b1)
    float h1[32];
    #pragma unroll
    for (int o = 0; o < 32; ++o) h1[o] = sm[OFF_B1 + o];
    #pragma unroll
    for (int i = 0; i < 32; ++i) {
        const float e = h0[i];
        const float4* wr = reinterpret_cast<const float4*>(&sm[OFF_W1 + i * 32]);
        #pragma unroll
        for (int o4 = 0; o4 < 8; ++o4) {
            const float4 w4 = wr[o4];
            h1[4*o4+0] = fmaf(e, w4.x, h1[4*o4+0]);
            h1[4*o4+1] = fmaf(e, w4.y, h1[4*o4+1]);
            h1[4*o4+2] = fmaf(e, w4.z, h1[4*o4+2]);
            h1[4*o4+3] = fmaf(e, w4.w, h1[4*o4+3]);
        }
    }
    #pragma unroll
    for (int o = 0; o < 32; ++o) h1[o] = fmaxf(h1[o], 0.f);

    // ---- layer 2: h2 = relu(h1 @ W2 + b2)  (reuse h0 storage)
    float h2[32];
    #pragma unroll
    for (int o = 0; o < 32; ++o) h2[o] = sm[OFF_B2 + o];
    #pragma unroll
    for (int i = 0; i < 32; ++i) {
        const float e = h1[i];
        const float4* wr = reinterpret_cast<const float4*>(&sm[OFF_W2 + i * 32]);
        #pragma unroll
        for (int o4 = 0; o4 < 8; ++o4) {
            const float4 w4 = wr[o4];
            h2[4*o4+0] = fmaf(e, w4.x, h2[4*o4+0]);
            h2[4*o4+1] = fmaf(e, w4.y, h2[4*o4+1]);
            h2[4*o4+2] = fmaf(e, w4.z, h2[4*o4+2]);
            h2[4*o4+3] = fmaf(e, w4.w, h2[4*o4+3]);
        }
    }
    #pragma unroll
    for (int o = 0; o < 32; ++o) h2[o] = fmaxf(h2[o], 0.f);

    // ---- output layer: pred = h2 @ W3 + b3   (W3 transposed in LDS -> per-j dot)
    float pred[33];
    #pragma unroll
    for (int j = 0; j < 33; ++j) {
        float acc = sm[OFF_B3 + j];
        const float4* wr = reinterpret_cast<const float4*>(&sm[OFF_W3T + j * 32]);
        #pragma unroll
        for (int i4 = 0; i4 < 8; ++i4) {
            const float4 w4 = wr[i4];
            acc = fmaf(h2[4*i4+0], w4.x, acc);
            acc = fmaf(h2[4*i4+1], w4.y, acc);
            acc = fmaf(h2[4*i4+2], w4.z, acc);
            acc = fmaf(h2[4*i4+3], w4.w, acc);
        }
        pred[j] = acc;
    }

    // ---- eps heads: he = relu(geom @ eW0[k] + eb0[k]); eps[k] = he @ eW1[k] + eb1[k]
    float epsv[2];
    #pragma unroll
    for (int k = 0; k < 2; ++k) {
        float he[32];
        #pragma unroll
        for (int hh = 0; hh < 32; ++hh) he[hh] = sm[OFF_EB0 + k * 32 + hh];
        #pragma unroll
        for (int f = 0; f < 32; ++f) {
            const float g = pred[1 + f];
            const float4* wr = reinterpret_cast<const float4*>(&sm[OFF_EW0 + k * 1024 + f * 32]);
            #pragma unroll
            for (int h4 = 0; h4 < 8; ++h4) {
                const float4 w4 = wr[h4];
                he[4*h4+0] = fmaf(g, w4.x, he[4*h4+0]);
                he[4*h4+1] = fmaf(g, w4.y, he[4*h4+1]);
                he[4*h4+2] = fmaf(g, w4.z, he[4*h4+2]);
                he[4*h4+3] = fmaf(g, w4.w, he[4*h4+3]);
            }
        }
        float acc = sm[OFF_EB1 + k];
        #pragma unroll
        for (int hh = 0; hh < 32; ++hh)
            acc = fmaf(fmaxf(he[hh], 0.f), sm[OFF_EW1 + k * 32 + hh], acc);
        epsv[k] = acc;
    }

    const float inner_eps = softplus_f(epsv[1]);
    const float outer_eps = -softplus_f(epsv[0]);
    const float sdf = pred[0];

    // ---- outputs: sdfs (N,3,1) | offsets (N,3,1) | geom_feats (N,32), concat flat
    float* osdf = out + (size_t)pid * 3;
    osdf[0] = sdf + (inner_eps + 1e-4f);   // sdf + cum_inner
    osdf[1] = sdf;
    osdf[2] = sdf + (outer_eps - 1e-4f);   // sdf + cum_outer

    float* ooff = out + (size_t)NPTS * 3 + (size_t)pid * 3;
    ooff[0] = inner_eps;
    ooff[1] = 0.f;
    ooff[2] = outer_eps;

    float* og = out + (size_t)NPTS * 6 + (size_t)pid * 32;
    #pragma unroll
    for (int f4 = 0; f4 < 8; ++f4) {
        float4 v;
        v.x = pred[1 + 4*f4 + 0];
        v.y = pred[1 + 4*f4 + 1];
        v.z = pred[1 + 4*f4 + 2];
        v.w = pred[1 + 4*f4 + 3];
        reinterpret_cast<float4*>(og)[f4] = v;
    }
}

extern "C" void kernel_launch(void* const* d_in, const int* in_sizes, int n_in,
                              void* d_out, int out_size, void* d_ws, size_t ws_size,
                              hipStream_t stream) {
    const float* points = (const float*)d_in[0];
    const float* table  = (const float*)d_in[1];
    const float* W0  = (const float*)d_in[2];
    const float* b0  = (const float*)d_in[3];
    const float* W1  = (const float*)d_in[4];
    const float* b1  = (const float*)d_in[5];
    const float* W2  = (const float*)d_in[6];
    const float* b2  = (const float*)d_in[7];
    const float* W3  = (const float*)d_in[8];
    const float* b3  = (const float*)d_in[9];
    const float* eW0 = (const float*)d_in[10];
    const float* eb0 = (const float*)d_in[11];
    const float* eW1 = (const float*)d_in[12];
    const float* eb1 = (const float*)d_in[13];
    float* out = (float*)d_out;

    // RES replicated in float64 exactly as numpy computes it
    ResParams rp;
    const double step = log(2048.0 / 16.0) / 23.0;
    for (int l = 0; l < NLVL; ++l)
        rp.r[l] = (float)floor(16.0 * exp((double)l * log(2048.0 / 16.0) / 23.0));
    (void)step; (void)in_sizes; (void)n_in; (void)out_size; (void)d_ws; (void)ws_size;

    fused_offsets_sdf<<<dim3(NPTS / 256), dim3(256), 0, stream>>>(
        points, table, W0, b0, W1, b1, W2, b2, W3, b3, eW0, eb0, eW1, eb1, out, rp);
}

// Round 2
// 472.664 us; speedup vs baseline: 1.0005x; 1.0005x over previous
//
#include <hip/hip_runtime.h>
#include <math.h>
#include <stdint.h>

#define NPTS   524288
#define TSZ    524288u
#define HMASK  (TSZ - 1u)
#define PRIME1 2654435761u
#define PRIME2 805459861u
#define NLVL   24

struct ResParams { float r[NLVL]; };

// ---------------- bf16 pack/unpack (RNE) ----------------
__device__ __forceinline__ uint32_t pack_bf16x2(float a, float b) {
    uint32_t ua = __float_as_uint(a);
    uint32_t ub = __float_as_uint(b);
    ua = (ua + 0x7FFFu + ((ua >> 16) & 1u)) >> 16;
    ub = (ub + 0x7FFFu + ((ub >> 16) & 1u)) >> 16;
    return (ub << 16) | (ua & 0xFFFFu);
}
__device__ __forceinline__ float bf16_lo(uint32_t v) { return __uint_as_float(v << 16); }
__device__ __forceinline__ float bf16_hi(uint32_t v) { return __uint_as_float(v & 0xFFFF0000u); }

__device__ __forceinline__ float softplus_f(float x) {
    return fmaxf(x, 0.f) + log1pf(expf(-fabsf(x)));
}

// ================= PASS 1: level-blocked hash gather =================
// blockIdx = level * 512 + chunk ; each thread: 4 points, 1 level.
__global__ __launch_bounds__(256)
void hash_gather_pass(const float* __restrict__ points,
                      const float* __restrict__ table,
                      uint32_t* __restrict__ enc, ResParams rp)
{
    const int bid   = blockIdx.x;
    const int lvl   = bid >> 9;          // /512
    const int chunk = bid & 511;
    const float res = rp.r[lvl];
    const float* __restrict__ tl = table + (size_t)lvl * (size_t)(TSZ * 2u);
    uint32_t* __restrict__ el = enc + (size_t)lvl * (size_t)NPTS;
    const int pbase = chunk * 1024 + threadIdx.x;

    #pragma unroll
    for (int k = 0; k < 4; ++k) {
        const int p = pbase + k * 256;
        const float x0 = points[p * 3 + 0] * 0.5f + 0.5f;
        const float y0 = points[p * 3 + 1] * 0.5f + 0.5f;
        const float z0 = points[p * 3 + 2] * 0.5f + 0.5f;
        const float sx = x0 * res, sy = y0 * res, sz = z0 * res;
        const float fx = floorf(sx), fy = floorf(sy), fz = floorf(sz);
        const float tx = sx - fx,  ty = sy - fy,  tz = sz - fz;
        const uint32_t cx = (uint32_t)fx, cy = (uint32_t)fy, cz = (uint32_t)fz;
        const uint32_t hy0 = cy * PRIME1, hy1 = (cy + 1u) * PRIME1;
        const uint32_t hz0 = cz * PRIME2, hz1 = (cz + 1u) * PRIME2;
        const float wx[2] = {1.f - tx, tx};
        const float wy[2] = {1.f - ty, ty};
        const float wz[2] = {1.f - tz, tz};

        float a0 = 0.f, a1 = 0.f;
        #pragma unroll
        for (int corner = 0; corner < 8; ++corner) {
            const uint32_t dx = (uint32_t)(corner & 1);
            const uint32_t dy = (uint32_t)((corner >> 1) & 1);
            const uint32_t dz = (uint32_t)((corner >> 2) & 1);
            const uint32_t idx = ((cx + dx) ^ (dy ? hy1 : hy0) ^ (dz ? hz1 : hz0)) & HMASK;
            const float2 f2 = *reinterpret_cast<const float2*>(tl + (size_t)idx * 2u);
            const float w = wx[dx] * wy[dy] * wz[dz];
            a0 = fmaf(w, f2.x, a0);
            a1 = fmaf(w, f2.y, a1);
        }
        el[p] = pack_bf16x2(a0, a1);
    }
}

// ================= PASS 2: MLP + eps heads + epilogue =================
// LDS layout (float offsets), all segment starts multiple of 4 (16B aligned)
#define OFF_W0   0      // 48*32 = 1536
#define OFF_B0   1536   // 32
#define OFF_W1   1568   // 1024
#define OFF_B1   2592   // 32
#define OFF_W2   2624   // 1024
#define OFF_B2   3648   // 32
#define OFF_W3T  3680   // transposed [33][32] = 1056
#define OFF_B3   4736   // 33 (pad->36)
#define OFF_EW0  4772   // 2048
#define OFF_EB0  6820   // 64
#define OFF_EW1  6884   // 64
#define OFF_EB1  6948   // 2 (pad->4)
#define SMEM_FLOATS 6952

__device__ __forceinline__ void stage_weights(float* sm, int t,
    const float* W0, const float* b0, const float* W1, const float* b1,
    const float* W2, const float* b2, const float* W3, const float* b3,
    const float* eW0, const float* eb0, const float* eW1, const float* eb1)
{
    for (int i = t; i < 1536; i += 256) sm[OFF_W0 + i] = W0[i];
    for (int i = t; i < 32;   i += 256) sm[OFF_B0 + i] = b0[i];
    for (int i = t; i < 1024; i += 256) sm[OFF_W1 + i] = W1[i];
    for (int i = t; i < 32;   i += 256) sm[OFF_B1 + i] = b1[i];
    for (int i = t; i < 1024; i += 256) sm[OFF_W2 + i] = W2[i];
    for (int i = t; i < 32;   i += 256) sm[OFF_B2 + i] = b2[i];
    for (int i = t; i < 1056; i += 256) {
        int r_ = i / 33, c_ = i % 33;
        sm[OFF_W3T + c_ * 32 + r_] = W3[i];
    }
    for (int i = t; i < 33;   i += 256) sm[OFF_B3 + i] = b3[i];
    for (int i = t; i < 2048; i += 256) sm[OFF_EW0 + i] = eW0[i];
    for (int i = t; i < 64;   i += 256) sm[OFF_EB0 + i] = eb0[i];
    for (int i = t; i < 64;   i += 256) sm[OFF_EW1 + i] = eW1[i];
    for (int i = t; i < 2;    i += 256) sm[OFF_EB1 + i] = eb1[i];
}

__device__ __forceinline__ void mlp_tail(const float* sm, float* h0, int pid,
                                         float* __restrict__ out)
{
    #pragma unroll
    for (int o = 0; o < 32; ++o) h0[o] = fmaxf(h0[o], 0.f);

    float h1[32];
    #pragma unroll
    for (int o = 0; o < 32; ++o) h1[o] = sm[OFF_B1 + o];
    #pragma unroll
    for (int i = 0; i < 32; ++i) {
        const float e = h0[i];
        const float4* wr = reinterpret_cast<const float4*>(&sm[OFF_W1 + i * 32]);
        #pragma unroll
        for (int o4 = 0; o4 < 8; ++o4) {
            const float4 w4 = wr[o4];
            h1[4*o4+0] = fmaf(e, w4.x, h1[4*o4+0]);
            h1[4*o4+1] = fmaf(e, w4.y, h1[4*o4+1]);
            h1[4*o4+2] = fmaf(e, w4.z, h1[4*o4+2]);
            h1[4*o4+3] = fmaf(e, w4.w, h1[4*o4+3]);
        }
    }
    #pragma unroll
    for (int o = 0; o < 32; ++o) h1[o] = fmaxf(h1[o], 0.f);

    float h2[32];
    #pragma unroll
    for (int o = 0; o < 32; ++o) h2[o] = sm[OFF_B2 + o];
    #pragma unroll
    for (int i = 0; i < 32; ++i) {
        const float e = h1[i];
        const float4* wr = reinterpret_cast<const float4*>(&sm[OFF_W2 + i * 32]);
        #pragma unroll
        for (int o4 = 0; o4 < 8; ++o4) {
            const float4 w4 = wr[o4];
            h2[4*o4+0] = fmaf(e, w4.x, h2[4*o4+0]);
            h2[4*o4+1] = fmaf(e, w4.y, h2[4*o4+1]);
            h2[4*o4+2] = fmaf(e, w4.z, h2[4*o4+2]);
            h2[4*o4+3] = fmaf(e, w4.w, h2[4*o4+3]);
        }
    }
    #pragma unroll
    for (int o = 0; o < 32; ++o) h2[o] = fmaxf(h2[o], 0.f);

    float pred[33];
    #pragma unroll
    for (int j = 0; j < 33; ++j) {
        float acc = sm[OFF_B3 + j];
        const float4* wr = reinterpret_cast<const float4*>(&sm[OFF_W3T + j * 32]);
        #pragma unroll
        for (int i4 = 0; i4 < 8; ++i4) {
            const float4 w4 = wr[i4];
            acc = fmaf(h2[4*i4+0], w4.x, acc);
            acc = fmaf(h2[4*i4+1], w4.y, acc);
            acc = fmaf(h2[4*i4+2], w4.z, acc);
            acc = fmaf(h2[4*i4+3], w4.w, acc);
        }
        pred[j] = acc;
    }

    float epsv[2];
    #pragma unroll
    for (int k = 0; k < 2; ++k) {
        float he[32];
        #pragma unroll
        for (int hh = 0; hh < 32; ++hh) he[hh] = sm[OFF_EB0 + k * 32 + hh];
        #pragma unroll
        for (int f = 0; f < 32; ++f) {
            const float g = pred[1 + f];
            const float4* wr = reinterpret_cast<const float4*>(&sm[OFF_EW0 + k * 1024 + f * 32]);
            #pragma unroll
            for (int h4 = 0; h4 < 8; ++h4) {
                const float4 w4 = wr[h4];
                he[4*h4+0] = fmaf(g, w4.x, he[4*h4+0]);
                he[4*h4+1] = fmaf(g, w4.y, he[4*h4+1]);
                he[4*h4+2] = fmaf(g, w4.z, he[4*h4+2]);
                he[4*h4+3] = fmaf(g, w4.w, he[4*h4+3]);
            }
        }
        float acc = sm[OFF_EB1 + k];
        #pragma unroll
        for (int hh = 0; hh < 32; ++hh)
            acc = fmaf(fmaxf(he[hh], 0.f), sm[OFF_EW1 + k * 32 + hh], acc);
        epsv[k] = acc;
    }

    const float inner_eps = softplus_f(epsv[1]);
    const float outer_eps = -softplus_f(epsv[0]);
    const float sdf = pred[0];

    float* osdf = out + (size_t)pid * 3;
    osdf[0] = sdf + (inner_eps + 1e-4f);
    osdf[1] = sdf;
    osdf[2] = sdf + (outer_eps - 1e-4f);

    float* ooff = out + (size_t)NPTS * 3 + (size_t)pid * 3;
    ooff[0] = inner_eps;
    ooff[1] = 0.f;
    ooff[2] = outer_eps;

    float* og = out + (size_t)NPTS * 6 + (size_t)pid * 32;
    #pragma unroll
    for (int f4 = 0; f4 < 8; ++f4) {
        float4 v;
        v.x = pred[1 + 4*f4 + 0];
        v.y = pred[1 + 4*f4 + 1];
        v.z = pred[1 + 4*f4 + 2];
        v.w = pred[1 + 4*f4 + 3];
        reinterpret_cast<float4*>(og)[f4] = v;
    }
}

__global__ __launch_bounds__(256)
void mlp_pass(const uint32_t* __restrict__ enc,
              const float* __restrict__ W0, const float* __restrict__ b0,
              const float* __restrict__ W1, const float* __restrict__ b1,
              const float* __restrict__ W2, const float* __restrict__ b2,
              const float* __restrict__ W3, const float* __restrict__ b3,
              const float* __restrict__ eW0, const float* __restrict__ eb0,
              const float* __restrict__ eW1, const float* __restrict__ eb1,
              float* __restrict__ out)
{
    __shared__ __align__(16) float sm[SMEM_FLOATS];
    const int t = threadIdx.x;
    stage_weights(sm, t, W0, b0, W1, b1, W2, b2, W3, b3, eW0, eb0, eW1, eb1);
    __syncthreads();

    const int pid = blockIdx.x * 256 + t;

    // prefetch all 24 packed feature words
    uint32_t fw[NLVL];
    #pragma unroll
    for (int l = 0; l < NLVL; ++l) fw[l] = enc[(size_t)l * NPTS + pid];

    float h0[32];
    #pragma unroll
    for (int o = 0; o < 32; ++o) h0[o] = sm[OFF_B0 + o];

    #pragma unroll
    for (int l = 0; l < NLVL; ++l) {
        const float a0 = bf16_lo(fw[l]);
        const float a1 = bf16_hi(fw[l]);
        const float4* w0a = reinterpret_cast<const float4*>(&sm[OFF_W0 + (2 * l) * 32]);
        const float4* w0b = reinterpret_cast<const float4*>(&sm[OFF_W0 + (2 * l + 1) * 32]);
        #pragma unroll
        for (int o4 = 0; o4 < 8; ++o4) {
            const float4 wa = w0a[o4];
            const float4 wb = w0b[o4];
            h0[4*o4+0] = fmaf(a0, wa.x, fmaf(a1, wb.x, h0[4*o4+0]));
            h0[4*o4+1] = fmaf(a0, wa.y, fmaf(a1, wb.y, h0[4*o4+1]));
            h0[4*o4+2] = fmaf(a0, wa.z, fmaf(a1, wb.z, h0[4*o4+2]));
            h0[4*o4+3] = fmaf(a0, wa.w, fmaf(a1, wb.w, h0[4*o4+3]));
        }
    }
    mlp_tail(sm, h0, pid, out);
}

// ================= Fallback: R1 fused kernel (if ws too small) =================
__global__ __launch_bounds__(256)
void fused_offsets_sdf(const float* __restrict__ points,
                       const float* __restrict__ table,
                       const float* __restrict__ W0, const float* __restrict__ b0,
                       const float* __restrict__ W1, const float* __restrict__ b1,
                       const float* __restrict__ W2, const float* __restrict__ b2,
                       const float* __restrict__ W3, const float* __restrict__ b3,
                       const float* __restrict__ eW0, const float* __restrict__ eb0,
                       const float* __restrict__ eW1, const float* __restrict__ eb1,
                       float* __restrict__ out, ResParams rp)
{
    __shared__ __align__(16) float sm[SMEM_FLOATS];
    const int t = threadIdx.x;
    stage_weights(sm, t, W0, b0, W1, b1, W2, b2, W3, b3, eW0, eb0, eW1, eb1);
    __syncthreads();

    const int pid = blockIdx.x * 256 + t;
    const float x0 = points[pid * 3 + 0] * 0.5f + 0.5f;
    const float y0 = points[pid * 3 + 1] * 0.5f + 0.5f;
    const float z0 = points[pid * 3 + 2] * 0.5f + 0.5f;

    float h0[32];
    #pragma unroll
    for (int o = 0; o < 32; ++o) h0[o] = sm[OFF_B0 + o];

    #pragma unroll 2
    for (int l = 0; l < NLVL; ++l) {
        const float res = rp.r[l];
        const float sx = x0 * res, sy = y0 * res, sz = z0 * res;
        const float fx = floorf(sx), fy = floorf(sy), fz = floorf(sz);
        const float tx = sx - fx,  ty = sy - fy,  tz = sz - fz;
        const uint32_t cx = (uint32_t)fx, cy = (uint32_t)fy, cz = (uint32_t)fz;
        const uint32_t hy0 = cy * PRIME1, hy1 = (cy + 1u) * PRIME1;
        const uint32_t hz0 = cz * PRIME2, hz1 = (cz + 1u) * PRIME2;
        const float wx[2] = {1.f - tx, tx};
        const float wy[2] = {1.f - ty, ty};
        const float wz[2] = {1.f - tz, tz};
        const float* tl = table + (size_t)l * (size_t)(TSZ * 2u);

        float a0 = 0.f, a1 = 0.f;
        #pragma unroll
        for (int corner = 0; corner < 8; ++corner) {
            const uint32_t dx = (uint32_t)(corner & 1);
            const uint32_t dy = (uint32_t)((corner >> 1) & 1);
            const uint32_t dz = (uint32_t)((corner >> 2) & 1);
            const uint32_t idx = ((cx + dx) ^ (dy ? hy1 : hy0) ^ (dz ? hz1 : hz0)) & HMASK;
            const float2 f2 = *reinterpret_cast<const float2*>(tl + (size_t)idx * 2u);
            const float w = wx[dx] * wy[dy] * wz[dz];
            a0 = fmaf(w, f2.x, a0);
            a1 = fmaf(w, f2.y, a1);
        }
        const float4* w0a = reinterpret_cast<const float4*>(&sm[OFF_W0 + (2 * l) * 32]);
        const float4* w0b = reinterpret_cast<const float4*>(&sm[OFF_W0 + (2 * l + 1) * 32]);
        #pragma unroll
        for (int o4 = 0; o4 < 8; ++o4) {
            const float4 wa = w0a[o4];
            const float4 wb = w0b[o4];
            h0[4*o4+0] = fmaf(a0, wa.x, fmaf(a1, wb.x, h0[4*o4+0]));
            h0[4*o4+1] = fmaf(a0, wa.y, fmaf(a1, wb.y, h0[4*o4+1]));
            h0[4*o4+2] = fmaf(a0, wa.z, fmaf(a1, wb.z, h0[4*o4+2]));
            h0[4*o4+3] = fmaf(a0, wa.w, fmaf(a1, wb.w, h0[4*o4+3]));
        }
    }
    mlp_tail(sm, h0, pid, out);
}

extern "C" void kernel_launch(void* const* d_in, const int* in_sizes, int n_in,
                              void* d_out, int out_size, void* d_ws, size_t ws_size,
                              hipStream_t stream) {
    const float* points = (const float*)d_in[0];
    const float* table  = (const float*)d_in[1];
    const float* W0  = (const float*)d_in[2];
    const float* b0  = (const float*)d_in[3];
    const float* W1  = (const float*)d_in[4];
    const float* b1  = (const float*)d_in[5];
    const float* W2  = (const float*)d_in[6];
    const float* b2  = (const float*)d_in[7];
    const float* W3  = (const float*)d_in[8];
    const float* b3  = (const float*)d_in[9];
    const float* eW0 = (const float*)d_in[10];
    const float* eb0 = (const float*)d_in[11];
    const float* eW1 = (const float*)d_in[12];
    const float* eb1 = (const float*)d_in[13];
    float* out = (float*)d_out;

    ResParams rp;
    for (int l = 0; l < NLVL; ++l)
        rp.r[l] = (float)floor(16.0 * exp((double)l * log(2048.0 / 16.0) / 23.0));
    (void)in_sizes; (void)n_in; (void)out_size;

    const size_t ws_needed = (size_t)NLVL * NPTS * sizeof(uint32_t);  // 50.3 MB
    if (ws_size >= ws_needed) {
        uint32_t* enc = (uint32_t*)d_ws;
        hash_gather_pass<<<dim3(NLVL * 512), dim3(256), 0, stream>>>(points, table, enc, rp);
        mlp_pass<<<dim3(NPTS / 256), dim3(256), 0, stream>>>(
            enc, W0, b0, W1, b1, W2, b2, W3, b3, eW0, eb0, eW1, eb1, out);
    } else {
        fused_offsets_sdf<<<dim3(NPTS / 256), dim3(256), 0, stream>>>(
            points, table, W0, b0, W1, b1, W2, b2, W3, b3, eW0, eb0, eW1, eb1, out, rp);
    }
}